// Round 2
// baseline (3181.180 us; speedup 1.0000x reference)
//
#include <hip/hip_runtime.h>
#include <hip/hip_bf16.h>
#include <hip/hip_cooperative_groups.h>
#include <math.h>

namespace cg = cooperative_groups;

#define BATCH 32
#define TSEQ  64
#define KATTR 5
#define VOCAB 32000
#define DE    300
#define DA    300
#define DI    2048
#define HDIM  512
#define G4    2048            // 4*H
#define WOFF  (DE + DI + DA)  // recurrent rows offset in lstm_kernel

// ---------------------------------------------------------------- utility
__global__ void zero_kernel(float* __restrict__ p, int n) {
    int i = blockIdx.x * blockDim.x + threadIdx.x;
    if (i < n) p[i] = 0.f;
}

// ---------------------------------------------------------------- K1: mean attr embedding
__global__ void mean_attr_kernel(const int* __restrict__ topk,
                                 const float* __restrict__ attr_emb,
                                 float* __restrict__ mean_attr) {
    int b = blockIdx.x;
    int tid = threadIdx.x;
    if (tid < DA) {
        float s = 0.f;
        #pragma unroll
        for (int q = 0; q < KATTR; ++q) {
            int a = topk[b * KATTR + q];
            s += attr_emb[(size_t)a * DA + tid];
        }
        mean_attr[b * DA + tid] = s / (float)KATTR;
    }
}

// ---------------------------------------------------------------- K2: zf[b][j] = bias + img@Wimg + mean_attr@Wattr
__launch_bounds__(256)
__global__ void zf_kernel(const float* __restrict__ img,
                          const float* __restrict__ mean_attr,
                          const float* __restrict__ Wk,
                          const float* __restrict__ bias,
                          float* __restrict__ zf) {
    int b = blockIdx.y;
    int j = blockIdx.x * 256 + threadIdx.x;
    float acc = bias[j];
    const float* wimg = Wk + (size_t)DE * G4 + j;
    const float* irow = img + b * DI;
    #pragma unroll 8
    for (int k = 0; k < DI; ++k) acc += irow[k] * wimg[(size_t)k * G4];
    const float* wattr = Wk + (size_t)(DE + DI) * G4 + j;
    const float* arow = mean_attr + b * DA;
    #pragma unroll 4
    for (int k = 0; k < DA; ++k) acc += arow[k] * wattr[(size_t)k * G4];
    zf[b * G4 + j] = acc;
}

// ---------------------------------------------------------------- Wh reshuffle: Whr[bid][k][jj]  jj = g*2+p, col = g*512 + bid*2 + p
__launch_bounds__(256)
__global__ void whr_kernel(const float* __restrict__ Wk, float* __restrict__ Whr) {
    const int bid = blockIdx.x;
    const int tid = threadIdx.x;
    for (int it = 0; it < 16; ++it) {
        int Q = it * 256 + tid;           // 0..4095
        int k = Q >> 3, jj = Q & 7;
        int g = jj >> 1, p = jj & 1;
        Whr[(size_t)bid * 4096 + Q] = Wk[(size_t)(WOFF + k) * G4 + g * HDIM + bid * 2 + p];
    }
}

// ---------------------------------------------------------------- tiled fp32 GEMM, 64x64x16, 256 thr, 4x4/thread
// PERROW: add = addv[(m>>6)*N + n]; else add = addv[n]
template<bool GATHER, bool PERROW>
__launch_bounds__(256)
__global__ void gemm_tile(const float* __restrict__ A,
                          const int* __restrict__ gidx,
                          const float* __restrict__ Bm,
                          const float* __restrict__ addv,
                          float* __restrict__ C,
                          int M, int N, int K, int lda) {
    __shared__ __align__(16) float As[16][68];
    __shared__ __align__(16) float Bs[16][68];
    const int tid = threadIdx.x;
    const int n0 = blockIdx.x * 64;
    const int m0 = blockIdx.y * 64;
    const int tx = tid & 15, ty = tid >> 4;
    const int ar  = tid >> 2;
    const int akq = (tid & 3) << 2;
    const int bkr = tid >> 4;
    const int bc  = (tid & 15) << 2;

    size_t arow;
    if (GATHER) arow = (size_t)gidx[m0 + ar] * (size_t)lda;
    else        arow = (size_t)(m0 + ar) * (size_t)lda;

    float a00=0,a01=0,a02=0,a03=0, a10=0,a11=0,a12=0,a13=0;
    float a20=0,a21=0,a22=0,a23=0, a30=0,a31=0,a32=0,a33=0;

    for (int k0 = 0; k0 < K; k0 += 16) {
        int ka = k0 + akq;
        float4 av;
        if (ka + 4 <= K) {
            av = *(const float4*)(A + arow + ka);
        } else {
            av.x = (ka + 0 < K) ? A[arow + ka + 0] : 0.f;
            av.y = (ka + 1 < K) ? A[arow + ka + 1] : 0.f;
            av.z = (ka + 2 < K) ? A[arow + ka + 2] : 0.f;
            av.w = (ka + 3 < K) ? A[arow + ka + 3] : 0.f;
        }
        As[akq + 0][ar] = av.x;
        As[akq + 1][ar] = av.y;
        As[akq + 2][ar] = av.z;
        As[akq + 3][ar] = av.w;

        int kb = k0 + bkr;
        float4 bv;
        if (kb < K) bv = *(const float4*)(Bm + (size_t)kb * N + n0 + bc);
        else { bv.x = bv.y = bv.z = bv.w = 0.f; }
        *(float4*)&Bs[bkr][bc] = bv;

        __syncthreads();
        #pragma unroll
        for (int kk = 0; kk < 16; ++kk) {
            const float4 a4 = *(const float4*)&As[kk][ty << 2];
            const float4 b4 = *(const float4*)&Bs[kk][tx << 2];
            a00 += a4.x * b4.x; a01 += a4.x * b4.y; a02 += a4.x * b4.z; a03 += a4.x * b4.w;
            a10 += a4.y * b4.x; a11 += a4.y * b4.y; a12 += a4.y * b4.z; a13 += a4.y * b4.w;
            a20 += a4.z * b4.x; a21 += a4.z * b4.y; a22 += a4.z * b4.z; a23 += a4.z * b4.w;
            a30 += a4.w * b4.x; a31 += a4.w * b4.y; a32 += a4.w * b4.z; a33 += a4.w * b4.w;
        }
        __syncthreads();
    }

    float accs[4][4] = {{a00,a01,a02,a03},{a10,a11,a12,a13},{a20,a21,a22,a23},{a30,a31,a32,a33}};
    const int n = n0 + (tx << 2);
    #pragma unroll
    for (int i = 0; i < 4; ++i) {
        int m = m0 + (ty << 2) + i;
        const float* av2 = PERROW ? (addv + (size_t)(m >> 6) * N) : addv;
        float4 o;
        o.x = accs[i][0] + av2[n + 0];
        o.y = accs[i][1] + av2[n + 1];
        o.z = accs[i][2] + av2[n + 2];
        o.w = accs[i][3] + av2[n + 3];
        *(float4*)(C + (size_t)m * N + n) = o;
    }
}

// ---------------------------------------------------------------- row compaction list
__global__ void build_rows(const int* __restrict__ lengths,
                           int* __restrict__ rowlist, int* __restrict__ mact) {
    __shared__ int len[BATCH];
    __shared__ int off[BATCH + 1];
    int tid = threadIdx.x;
    if (tid < BATCH) len[tid] = lengths[tid];
    __syncthreads();
    if (tid == 0) {
        int s = 0;
        for (int b = 0; b < BATCH; ++b) { off[b] = s; s += len[b]; }
        off[BATCH] = s;
        *mact = s;
    }
    __syncthreads();
    int total = off[BATCH];
    for (int i = tid; i < BATCH * TSEQ; i += 256) {
        int b = i >> 6, t = i & 63;
        if (t < len[b]) rowlist[off[b] + t] = i;
    }
    for (int i = tid; i < BATCH * TSEQ; i += 256) {
        if (i >= total) rowlist[i] = 0;
    }
}

// ---------------------------------------------------------------- persistent cooperative LSTM scan
// 256 blocks (1/CU, LDS-bound), 256 thr. Block bid owns kouts {bid*2, bid*2+1};
// j-cols jj=g*2+p -> g*512 + bid*2 + p. W staged to LDS ONCE; c lives in registers
// across all 64 steps; h ping-pongs between hb0/hb1 with one grid.sync per step.
__launch_bounds__(256, 1)
__global__ void lstm_scan(const float* __restrict__ z_pre,   // [B*T][2048]
                          const float* __restrict__ Whr,     // [256][512][8]
                          float* __restrict__ hb0,           // [512][32] (zeroed)
                          float* __restrict__ hb1,           // [512][32]
                          float* __restrict__ h_seq,         // [B*T][512]
                          const int* __restrict__ lengths) {
    __shared__ __align__(16) float hsT[HDIM][36];   // [k][b], stride 36 (144B)
    __shared__ __align__(16) float wsm[HDIM][12];   // [k][jj], stride 12 (48B)
    __shared__ __align__(16) float zp[16 * 260];    // [kseg][tile*16+e], row pad +4
    __shared__ float zfull[BATCH][8];
    const int bid = blockIdx.x;
    const int tid = threadIdx.x;
    cg::grid_group grid = cg::this_grid();

    // stage W slice once: 4096 floats contiguous
    const float* wsrc = Whr + (size_t)bid * 4096;
    #pragma unroll
    for (int it = 0; it < 4; ++it) {
        int Q = it * 256 + tid;          // 0..1023
        int k = Q >> 1, jjq = Q & 1;
        float4 v = *(const float4*)(wsrc + (size_t)Q * 4);
        *(float4*)&wsm[k][jjq * 4] = v;
    }

    // per-thread gate state (tid<64): thread owns (gb, gkk) for the whole scan
    int glen = 0, gb = 0, gkk = 0;
    float c_reg = 0.f;
    const float* zr = nullptr;
    if (tid < 64) {
        gb = tid & 31;
        int kp = tid >> 5;
        gkk = bid * 2 + kp;
        glen = lengths[gb];
        zr = z_pre + ((size_t)(gb * TSEQ)) * G4 + gkk;
    }

    // compute-phase thread mapping (constant across steps)
    const int kseg = tid >> 4;
    const int tile = tid & 15;
    const int b0 = (tile >> 1) << 2;
    const int j0 = (tile & 1) << 2;
    const int kb = kseg << 5;
    // reduce-phase mapping
    const int rb = tid & 31, rjj = tid >> 5;
    const int tile2 = ((rb >> 2) << 1) + (rjj >> 2);
    const int e = ((rb & 3) << 2) + (rjj & 3);

    for (int t = 0; t < TSEQ; ++t) {
        const float* hin  = (t & 1) ? hb1 : hb0;
        float*       hout = (t & 1) ? hb0 : hb1;

        // early scalar prefetch of z_pre for the gate phase
        float zp4[4] = {0, 0, 0, 0};
        if (tid < 64) {
            const float* z = zr + (size_t)t * G4;
            zp4[0] = z[0 * HDIM];
            zp4[1] = z[1 * HDIM];
            zp4[2] = z[2 * HDIM];
            zp4[3] = z[3 * HDIM];
        }

        // stage h: 16384 floats, coalesced float4
        #pragma unroll
        for (int it = 0; it < 16; ++it) {
            int Q = it * 256 + tid;          // quad index; addr = 4Q floats
            int k = Q >> 3, bq = Q & 7;
            float4 v = *(const float4*)(hin + (size_t)Q * 4);
            *(float4*)&hsT[k][bq * 4] = v;
        }
        __syncthreads();

        // compute: thread = (kseg, tile); tile -> 4b x 4j
        {
            float a00=0,a01=0,a02=0,a03=0, a10=0,a11=0,a12=0,a13=0;
            float a20=0,a21=0,a22=0,a23=0, a30=0,a31=0,a32=0,a33=0;
            #pragma unroll 8
            for (int kk = 0; kk < 32; ++kk) {
                const int k = kb + kk;
                const float4 h4 = *(const float4*)&hsT[k][b0];
                const float4 w4 = *(const float4*)&wsm[k][j0];
                a00 += h4.x * w4.x; a01 += h4.x * w4.y; a02 += h4.x * w4.z; a03 += h4.x * w4.w;
                a10 += h4.y * w4.x; a11 += h4.y * w4.y; a12 += h4.y * w4.z; a13 += h4.y * w4.w;
                a20 += h4.z * w4.x; a21 += h4.z * w4.y; a22 += h4.z * w4.z; a23 += h4.z * w4.w;
                a30 += h4.w * w4.x; a31 += h4.w * w4.y; a32 += h4.w * w4.z; a33 += h4.w * w4.w;
            }
            float* zpr = &zp[kseg * 260 + tile * 16];
            *(float4*)(zpr + 0)  = make_float4(a00, a01, a02, a03);
            *(float4*)(zpr + 4)  = make_float4(a10, a11, a12, a13);
            *(float4*)(zpr + 8)  = make_float4(a20, a21, a22, a23);
            *(float4*)(zpr + 12) = make_float4(a30, a31, a32, a33);
        }
        __syncthreads();

        // reduce 16 kseg partials -> zfull[b][jj]
        {
            float s = 0.f;
            #pragma unroll
            for (int ks = 0; ks < 16; ++ks) s += zp[ks * 260 + tile2 * 16 + e];
            zfull[rb][rjj] = s;
        }
        __syncthreads();

        // gate math (wave 0): thread (gb, kp)
        if (tid < 64) {
            float zi = zfull[gb][0 * 2 + (tid >> 5)] + zp4[0];
            float zF = zfull[gb][1 * 2 + (tid >> 5)] + zp4[1];
            float zg = zfull[gb][2 * 2 + (tid >> 5)] + zp4[2];
            float zo = zfull[gb][3 * 2 + (tid >> 5)] + zp4[3];
            float si = 1.f / (1.f + expf(-zi));
            float sf = 1.f / (1.f + expf(-zF));
            float so = 1.f / (1.f + expf(-zo));
            float c_new = sf * c_reg + si * tanhf(zg);
            float h_new = so * tanhf(c_new);
            c_reg = c_new;
            hout[gkk * BATCH + gb] = h_new;
            h_seq[((size_t)(gb * TSEQ + t)) * HDIM + gkk] = (t < glen) ? h_new : 0.f;
        }
        grid.sync();
    }
}

// ---------------------------------------------------------------- fill masked logits rows with bias
__launch_bounds__(256)
__global__ void fill_masked(const int* __restrict__ lengths,
                            const float* __restrict__ blog,
                            float* __restrict__ logits) {
    int row = blockIdx.x;
    int b = row >> 6, t = row & 63;
    if (t < lengths[b]) return;
    float* p = logits + (size_t)row * VOCAB;
    for (int v = threadIdx.x * 4; v < VOCAB; v += 256 * 4) {
        float4 o;
        o.x = blog[v + 0]; o.y = blog[v + 1]; o.z = blog[v + 2]; o.w = blog[v + 3];
        *(float4*)(p + v) = o;
    }
}

// ---------------------------------------------------------------- logits GEMM over compacted rows
// 128x128 tile, 256 thr, 8x8 per thread (split 4+64), XCD-chunked swizzled 1-D grid.
__launch_bounds__(256)
__global__ void gemm_logits128(const float* __restrict__ A,      // h_seq
                               const int* __restrict__ rowlist,
                               const int* __restrict__ mactp,
                               const float* __restrict__ Bm,     // W_logits
                               const float* __restrict__ blog,
                               float* __restrict__ C) {
    const int Mact = *mactp;
    // bijective XCD-chunk swizzle (nwg = 4000, 4000 % 8 == 0)
    const int chunk = gridDim.x >> 3;                 // 500
    const int L = (blockIdx.x & 7) * chunk + (blockIdx.x >> 3);
    const int m0 = (L & 15) * 128;                    // m-tile fast
    const int n0 = (L >> 4) * 128;                    // n-tile slow
    if (m0 >= Mact) return;

    __shared__ __align__(16) float As[16][132];       // [k][m]
    __shared__ __align__(16) float Bs[16][132];       // [k][n]
    const int tid = threadIdx.x;
    const int tx = tid & 15, ty = tid >> 4;

    const int am  = tid >> 2;                         // 0..63
    const int akq = (tid & 3) << 2;                   // 0,4,8,12
    const size_t arow0 = (size_t)rowlist[m0 + am]      * HDIM;
    const size_t arow1 = (size_t)rowlist[m0 + 64 + am] * HDIM;
    const int bk = tid >> 5;                          // 0..7
    const int bc = (tid & 31) << 2;                   // 0..124

    float c00[4][4] = {}, c01[4][4] = {}, c10[4][4] = {}, c11[4][4] = {};

    for (int k0 = 0; k0 < HDIM; k0 += 16) {
        const float4 av0 = *(const float4*)(A + arow0 + k0 + akq);
        const float4 av1 = *(const float4*)(A + arow1 + k0 + akq);
        As[akq + 0][am] = av0.x;
        As[akq + 1][am] = av0.y;
        As[akq + 2][am] = av0.z;
        As[akq + 3][am] = av0.w;
        As[akq + 0][64 + am] = av1.x;
        As[akq + 1][64 + am] = av1.y;
        As[akq + 2][64 + am] = av1.z;
        As[akq + 3][64 + am] = av1.w;
        const float4 bv0 = *(const float4*)(Bm + (size_t)(k0 + bk)     * VOCAB + n0 + bc);
        const float4 bv1 = *(const float4*)(Bm + (size_t)(k0 + 8 + bk) * VOCAB + n0 + bc);
        *(float4*)&Bs[bk][bc]     = bv0;
        *(float4*)&Bs[bk + 8][bc] = bv1;
        __syncthreads();
        #pragma unroll
        for (int kk = 0; kk < 16; ++kk) {
            const float4 aL = *(const float4*)&As[kk][ty << 2];
            const float4 aH = *(const float4*)&As[kk][64 + (ty << 2)];
            const float4 bL = *(const float4*)&Bs[kk][tx << 2];
            const float4 bH = *(const float4*)&Bs[kk][64 + (tx << 2)];
            const float a_[8] = {aL.x, aL.y, aL.z, aL.w, aH.x, aH.y, aH.z, aH.w};
            const float b_[8] = {bL.x, bL.y, bL.z, bL.w, bH.x, bH.y, bH.z, bH.w};
            #pragma unroll
            for (int i = 0; i < 4; ++i) {
                #pragma unroll
                for (int j = 0; j < 4; ++j) {
                    c00[i][j] += a_[i]     * b_[j];
                    c01[i][j] += a_[i]     * b_[4 + j];
                    c10[i][j] += a_[4 + i] * b_[j];
                    c11[i][j] += a_[4 + i] * b_[4 + j];
                }
            }
        }
        __syncthreads();
    }

    const int nL = n0 + (tx << 2);
    const int nH = nL + 64;
    const float4 gL = *(const float4*)(blog + nL);
    const float4 gH = *(const float4*)(blog + nH);
    const float gLa[4] = {gL.x, gL.y, gL.z, gL.w};
    const float gHa[4] = {gH.x, gH.y, gH.z, gH.w};
    #pragma unroll
    for (int i = 0; i < 4; ++i) {
        const int mL = m0 + (ty << 2) + i;
        if (mL < Mact) {
            const size_t rm = (size_t)rowlist[mL] * VOCAB;
            float4 oL, oH;
            oL.x = c00[i][0] + gLa[0]; oL.y = c00[i][1] + gLa[1];
            oL.z = c00[i][2] + gLa[2]; oL.w = c00[i][3] + gLa[3];
            oH.x = c01[i][0] + gHa[0]; oH.y = c01[i][1] + gHa[1];
            oH.z = c01[i][2] + gHa[2]; oH.w = c01[i][3] + gHa[3];
            *(float4*)(C + rm + nL) = oL;
            *(float4*)(C + rm + nH) = oH;
        }
        const int mH = mL + 64;
        if (mH < Mact) {
            const size_t rm = (size_t)rowlist[mH] * VOCAB;
            float4 oL, oH;
            oL.x = c10[i][0] + gLa[0]; oL.y = c10[i][1] + gLa[1];
            oL.z = c10[i][2] + gLa[2]; oL.w = c10[i][3] + gLa[3];
            oH.x = c11[i][0] + gHa[0]; oH.y = c11[i][1] + gHa[1];
            oH.z = c11[i][2] + gHa[2]; oH.w = c11[i][3] + gHa[3];
            *(float4*)(C + rm + nL) = oL;
            *(float4*)(C + rm + nH) = oH;
        }
    }
}

// ---------------------------------------------------------------- argmax per row (first occurrence)
__launch_bounds__(256)
__global__ void argmax_kernel(const float* __restrict__ logits, float* __restrict__ outa) {
    const int row = blockIdx.x;
    const int tid = threadIdx.x;
    const float* p = logits + (size_t)row * VOCAB;
    float bv = -INFINITY; int bi = VOCAB;
    for (int v = tid; v < VOCAB; v += 256) {
        float x = p[v];
        if (x > bv) { bv = x; bi = v; }
    }
    __shared__ float sv[256];
    __shared__ int   si[256];
    sv[tid] = bv; si[tid] = bi;
    __syncthreads();
    for (int s = 128; s > 0; s >>= 1) {
        if (tid < s) {
            if (sv[tid + s] > sv[tid] || (sv[tid + s] == sv[tid] && si[tid + s] < si[tid])) {
                sv[tid] = sv[tid + s]; si[tid] = si[tid + s];
            }
        }
        __syncthreads();
    }
    if (tid == 0) outa[row] = (float)si[0];
}

// ---------------------------------------------------------------- launcher
extern "C" void kernel_launch(void* const* d_in, const int* in_sizes, int n_in,
                              void* d_out, int out_size, void* d_ws, size_t ws_size,
                              hipStream_t stream) {
    const int*   topk     = (const int*)d_in[0];
    const float* img      = (const float*)d_in[1];
    const int*   seq      = (const int*)d_in[2];
    const int*   lengths  = (const int*)d_in[3];
    const float* word_emb = (const float*)d_in[4];
    const float* attr_emb = (const float*)d_in[5];
    const float* Wk       = (const float*)d_in[6];
    const float* bias     = (const float*)d_in[7];
    const float* Wlog     = (const float*)d_in[8];
    const float* blog     = (const float*)d_in[9];

    float* out_logits = (float*)d_out;
    float* out_argmax = out_logits + (size_t)BATCH * TSEQ * VOCAB;

    // ws layout (floats): mean_attr | zf | cbuf | hb0 | hb1 | h_seq | Whr | rowlist | mact
    float* ws        = (float*)d_ws;
    float* mean_attr = ws;
    float* zf        = mean_attr + BATCH * DA;              // 9600
    float* cbuf      = zf + BATCH * G4;                     // 65536 (unused now; layout kept)
    float* hb0       = cbuf + HDIM * BATCH;                 // 16384
    float* hb1       = hb0 + HDIM * BATCH;
    float* h_seq     = hb1 + HDIM * BATCH;
    float* Whr       = h_seq + (size_t)BATCH * TSEQ * HDIM; // 4 MB
    int*   rowlist   = (int*)(Whr + (size_t)256 * 4096);
    int*   mact      = rowlist + BATCH * TSEQ;
    // z_pre [2048 rows][2048 j] staged in d_out's logits region; fully consumed
    // by the scan before fill/logits overwrite it.
    float* z_pre     = out_logits;

    // zero h0 ping-pong buffers (c lives in registers now)
    zero_kernel<<<dim3((2 * HDIM * BATCH + 255) / 256), 256, 0, stream>>>(hb0, 2 * HDIM * BATCH);

    build_rows<<<1, 256, 0, stream>>>(lengths, rowlist, mact);

    whr_kernel<<<dim3(256), 256, 0, stream>>>(Wk, Whr);

    mean_attr_kernel<<<dim3(BATCH), 320, 0, stream>>>(topk, attr_emb, mean_attr);

    zf_kernel<<<dim3(G4 / 256, BATCH), 256, 0, stream>>>(img, mean_attr, Wk, bias, zf);

    // z_pre[b*T+t][j] = word_emb[seq]@Wx + zf[b][j]
    gemm_tile<true, true><<<dim3(G4 / 64, (BATCH * TSEQ) / 64), 256, 0, stream>>>(
        word_emb, seq, Wk, zf, z_pre, BATCH * TSEQ, G4, DE, DE);

    // persistent cooperative scan: 1 launch, grid.sync between steps
    {
        void* kargs[] = {(void*)&z_pre, (void*)&Whr, (void*)&hb0, (void*)&hb1,
                         (void*)&h_seq, (void*)&lengths};
        hipLaunchCooperativeKernel((const void*)lstm_scan, dim3(256), dim3(256),
                                   kargs, 0, stream);
    }

    fill_masked<<<dim3(BATCH * TSEQ), 256, 0, stream>>>(lengths, blog, out_logits);

    // 128x128 tile, m-fast + XCD-chunked swizzle: 4000 blocks
    gemm_logits128<<<dim3((VOCAB / 128) * ((BATCH * TSEQ) / 128)), 256, 0, stream>>>(
        h_seq, rowlist, mact, Wlog, blog, out_logits);

    argmax_kernel<<<dim3(BATCH * TSEQ), 256, 0, stream>>>(out_logits, out_argmax);
}

// Round 3
// 2445.882 us; speedup vs baseline: 1.3006x; 1.3006x over previous
//
#include <hip/hip_runtime.h>
#include <hip/hip_bf16.h>
#include <math.h>

#define BATCH 32
#define TSEQ  64
#define KATTR 5
#define VOCAB 32000
#define DE    300
#define DA    300
#define DI    2048
#define HDIM  512
#define G4    2048            // 4*H
#define WOFF  (DE + DI + DA)  // recurrent rows offset in lstm_kernel

// ---------------------------------------------------------------- utility
__global__ void zero_kernel(float* __restrict__ p, int n) {
    int i = blockIdx.x * blockDim.x + threadIdx.x;
    if (i < n) p[i] = 0.f;
}

// ---------------------------------------------------------------- K1: mean attr embedding
__global__ void mean_attr_kernel(const int* __restrict__ topk,
                                 const float* __restrict__ attr_emb,
                                 float* __restrict__ mean_attr) {
    int b = blockIdx.x;
    int tid = threadIdx.x;
    if (tid < DA) {
        float s = 0.f;
        #pragma unroll
        for (int q = 0; q < KATTR; ++q) {
            int a = topk[b * KATTR + q];
            s += attr_emb[(size_t)a * DA + tid];
        }
        mean_attr[b * DA + tid] = s / (float)KATTR;
    }
}

// ---------------------------------------------------------------- K2: zf[b][j] = bias + img@Wimg + mean_attr@Wattr
__launch_bounds__(256)
__global__ void zf_kernel(const float* __restrict__ img,
                          const float* __restrict__ mean_attr,
                          const float* __restrict__ Wk,
                          const float* __restrict__ bias,
                          float* __restrict__ zf) {
    int b = blockIdx.y;
    int j = blockIdx.x * 256 + threadIdx.x;
    float acc = bias[j];
    const float* wimg = Wk + (size_t)DE * G4 + j;
    const float* irow = img + b * DI;
    #pragma unroll 8
    for (int k = 0; k < DI; ++k) acc += irow[k] * wimg[(size_t)k * G4];
    const float* wattr = Wk + (size_t)(DE + DI) * G4 + j;
    const float* arow = mean_attr + b * DA;
    #pragma unroll 4
    for (int k = 0; k < DA; ++k) acc += arow[k] * wattr[(size_t)k * G4];
    zf[b * G4 + j] = acc;
}

// ---------------------------------------------------------------- Wh reshuffle: Whr[bid][k][jj]  jj = g*2+p, col = g*512 + bid*2 + p
__launch_bounds__(256)
__global__ void whr_kernel(const float* __restrict__ Wk, float* __restrict__ Whr) {
    const int bid = blockIdx.x;
    const int tid = threadIdx.x;
    for (int it = 0; it < 16; ++it) {
        int Q = it * 256 + tid;           // 0..4095
        int k = Q >> 3, jj = Q & 7;
        int g = jj >> 1, p = jj & 1;
        Whr[(size_t)bid * 4096 + Q] = Wk[(size_t)(WOFF + k) * G4 + g * HDIM + bid * 2 + p];
    }
}

// ---------------------------------------------------------------- tiled fp32 GEMM, 64x64x16, 256 thr, 4x4/thread
// PERROW: add = addv[(m>>6)*N + n]; else add = addv[n]
template<bool GATHER, bool PERROW>
__launch_bounds__(256)
__global__ void gemm_tile(const float* __restrict__ A,
                          const int* __restrict__ gidx,
                          const float* __restrict__ Bm,
                          const float* __restrict__ addv,
                          float* __restrict__ C,
                          int M, int N, int K, int lda) {
    __shared__ __align__(16) float As[16][68];
    __shared__ __align__(16) float Bs[16][68];
    const int tid = threadIdx.x;
    const int n0 = blockIdx.x * 64;
    const int m0 = blockIdx.y * 64;
    const int tx = tid & 15, ty = tid >> 4;
    const int ar  = tid >> 2;
    const int akq = (tid & 3) << 2;
    const int bkr = tid >> 4;
    const int bc  = (tid & 15) << 2;

    size_t arow;
    if (GATHER) arow = (size_t)gidx[m0 + ar] * (size_t)lda;
    else        arow = (size_t)(m0 + ar) * (size_t)lda;

    float a00=0,a01=0,a02=0,a03=0, a10=0,a11=0,a12=0,a13=0;
    float a20=0,a21=0,a22=0,a23=0, a30=0,a31=0,a32=0,a33=0;

    for (int k0 = 0; k0 < K; k0 += 16) {
        int ka = k0 + akq;
        float4 av;
        if (ka + 4 <= K) {
            av = *(const float4*)(A + arow + ka);
        } else {
            av.x = (ka + 0 < K) ? A[arow + ka + 0] : 0.f;
            av.y = (ka + 1 < K) ? A[arow + ka + 1] : 0.f;
            av.z = (ka + 2 < K) ? A[arow + ka + 2] : 0.f;
            av.w = (ka + 3 < K) ? A[arow + ka + 3] : 0.f;
        }
        As[akq + 0][ar] = av.x;
        As[akq + 1][ar] = av.y;
        As[akq + 2][ar] = av.z;
        As[akq + 3][ar] = av.w;

        int kb = k0 + bkr;
        float4 bv;
        if (kb < K) bv = *(const float4*)(Bm + (size_t)kb * N + n0 + bc);
        else { bv.x = bv.y = bv.z = bv.w = 0.f; }
        *(float4*)&Bs[bkr][bc] = bv;

        __syncthreads();
        #pragma unroll
        for (int kk = 0; kk < 16; ++kk) {
            const float4 a4 = *(const float4*)&As[kk][ty << 2];
            const float4 b4 = *(const float4*)&Bs[kk][tx << 2];
            a00 += a4.x * b4.x; a01 += a4.x * b4.y; a02 += a4.x * b4.z; a03 += a4.x * b4.w;
            a10 += a4.y * b4.x; a11 += a4.y * b4.y; a12 += a4.y * b4.z; a13 += a4.y * b4.w;
            a20 += a4.z * b4.x; a21 += a4.z * b4.y; a22 += a4.z * b4.z; a23 += a4.z * b4.w;
            a30 += a4.w * b4.x; a31 += a4.w * b4.y; a32 += a4.w * b4.z; a33 += a4.w * b4.w;
        }
        __syncthreads();
    }

    float accs[4][4] = {{a00,a01,a02,a03},{a10,a11,a12,a13},{a20,a21,a22,a23},{a30,a31,a32,a33}};
    const int n = n0 + (tx << 2);
    #pragma unroll
    for (int i = 0; i < 4; ++i) {
        int m = m0 + (ty << 2) + i;
        const float* av2 = PERROW ? (addv + (size_t)(m >> 6) * N) : addv;
        float4 o;
        o.x = accs[i][0] + av2[n + 0];
        o.y = accs[i][1] + av2[n + 1];
        o.z = accs[i][2] + av2[n + 2];
        o.w = accs[i][3] + av2[n + 3];
        *(float4*)(C + (size_t)m * N + n) = o;
    }
}

// ---------------------------------------------------------------- row compaction list
__global__ void build_rows(const int* __restrict__ lengths,
                           int* __restrict__ rowlist, int* __restrict__ mact) {
    __shared__ int len[BATCH];
    __shared__ int off[BATCH + 1];
    int tid = threadIdx.x;
    if (tid < BATCH) len[tid] = lengths[tid];
    __syncthreads();
    if (tid == 0) {
        int s = 0;
        for (int b = 0; b < BATCH; ++b) { off[b] = s; s += len[b]; }
        off[BATCH] = s;
        *mact = s;
    }
    __syncthreads();
    int total = off[BATCH];
    for (int i = tid; i < BATCH * TSEQ; i += 256) {
        int b = i >> 6, t = i & 63;
        if (t < len[b]) rowlist[off[b] + t] = i;
    }
    for (int i = tid; i < BATCH * TSEQ; i += 256) {
        if (i >= total) rowlist[i] = 0;
    }
}

// ---------------------------------------------------------------- custom grid barrier
// bar layout (ints): gcnt[g] at g*32 (g=0..31, 128B apart), rcnt at 2048, epoch at 2080.
// Monotonic counters, no reset: group g full for step t when its counter hits 8(t+1).
__device__ __forceinline__ void gridbar(int* __restrict__ bar, int t, int bid) {
    __syncthreads();                       // drains block's global writes (vmcnt(0) before s_barrier)
    if (threadIdx.x == 0) {
        __threadfence();                   // agent-scope release of h writes
        const int g = bid >> 3;
        int old = atomicAdd(&bar[g * 32], 1);
        if (old == t * 8 + 7) {
            int ro = atomicAdd(&bar[2048], 1);
            if (ro == t * 32 + 31) {
                __hip_atomic_store(&bar[2080], t + 1, __ATOMIC_RELEASE, __HIP_MEMORY_SCOPE_AGENT);
            }
        }
        while (__hip_atomic_load(&bar[2080], __ATOMIC_ACQUIRE, __HIP_MEMORY_SCOPE_AGENT) <= t) {
            __builtin_amdgcn_s_sleep(2);
        }
        __threadfence();                   // acquire: invalidate stale cached h
    }
    __syncthreads();
}

// ---------------------------------------------------------------- persistent LSTM scan (custom barrier)
// 256 blocks (1/CU via LDS), 256 thr. Block bid owns kouts {bid*2, bid*2+1};
// W staged to LDS once; c in registers; h ping-pongs hb0/hb1, one gridbar per step.
// Launched cooperatively ONLY for the co-residency guarantee.
__launch_bounds__(256, 1)
__global__ void lstm_scan(const float* __restrict__ z_pre,   // [B*T][2048]
                          const float* __restrict__ Whr,     // [256][512][8]
                          float* __restrict__ hb0,           // [512][32] (zeroed)
                          float* __restrict__ hb1,           // [512][32]
                          float* __restrict__ h_seq,         // [B*T][512]
                          const int* __restrict__ lengths,
                          int* __restrict__ bar) {
    __shared__ __align__(16) float hsT[HDIM][36];   // [k][b], stride 36 (144B)
    __shared__ __align__(16) float wsm[HDIM][12];   // [k][jj], stride 12 (48B)
    __shared__ __align__(16) float zp[16 * 260];    // [kseg][tile*16+e], row pad +4
    __shared__ float zfull[BATCH][8];
    const int bid = blockIdx.x;
    const int tid = threadIdx.x;

    // stage W slice once: 4096 floats contiguous
    const float* wsrc = Whr + (size_t)bid * 4096;
    #pragma unroll
    for (int it = 0; it < 4; ++it) {
        int Q = it * 256 + tid;          // 0..1023
        int k = Q >> 1, jjq = Q & 1;
        float4 v = *(const float4*)(wsrc + (size_t)Q * 4);
        *(float4*)&wsm[k][jjq * 4] = v;
    }

    // per-thread gate state (tid<64): thread owns (gb, gkk) for the whole scan
    int glen = 0, gb = 0, gkk = 0;
    float c_reg = 0.f;
    const float* zr = nullptr;
    if (tid < 64) {
        gb = tid & 31;
        int kp = tid >> 5;
        gkk = bid * 2 + kp;
        glen = lengths[gb];
        zr = z_pre + ((size_t)(gb * TSEQ)) * G4 + gkk;
    }

    // compute-phase thread mapping (constant across steps)
    const int kseg = tid >> 4;
    const int tile = tid & 15;
    const int b0 = (tile >> 1) << 2;
    const int j0 = (tile & 1) << 2;
    const int kb = kseg << 5;
    // reduce-phase mapping
    const int rb = tid & 31, rjj = tid >> 5;
    const int tile2 = ((rb >> 2) << 1) + (rjj >> 2);
    const int e = ((rb & 3) << 2) + (rjj & 3);

    for (int t = 0; t < TSEQ; ++t) {
        const float* hin  = (t & 1) ? hb1 : hb0;
        float*       hout = (t & 1) ? hb0 : hb1;

        // early scalar prefetch of z_pre for the gate phase
        float zp4[4] = {0, 0, 0, 0};
        if (tid < 64) {
            const float* z = zr + (size_t)t * G4;
            zp4[0] = z[0 * HDIM];
            zp4[1] = z[1 * HDIM];
            zp4[2] = z[2 * HDIM];
            zp4[3] = z[3 * HDIM];
        }

        // stage h: 16384 floats, coalesced float4
        #pragma unroll
        for (int it = 0; it < 16; ++it) {
            int Q = it * 256 + tid;          // quad index; addr = 4Q floats
            int k = Q >> 3, bq = Q & 7;
            float4 v = *(const float4*)(hin + (size_t)Q * 4);
            *(float4*)&hsT[k][bq * 4] = v;
        }
        __syncthreads();

        // compute: thread = (kseg, tile); tile -> 4b x 4j
        {
            float a00=0,a01=0,a02=0,a03=0, a10=0,a11=0,a12=0,a13=0;
            float a20=0,a21=0,a22=0,a23=0, a30=0,a31=0,a32=0,a33=0;
            #pragma unroll 8
            for (int kk = 0; kk < 32; ++kk) {
                const int k = kb + kk;
                const float4 h4 = *(const float4*)&hsT[k][b0];
                const float4 w4 = *(const float4*)&wsm[k][j0];
                a00 += h4.x * w4.x; a01 += h4.x * w4.y; a02 += h4.x * w4.z; a03 += h4.x * w4.w;
                a10 += h4.y * w4.x; a11 += h4.y * w4.y; a12 += h4.y * w4.z; a13 += h4.y * w4.w;
                a20 += h4.z * w4.x; a21 += h4.z * w4.y; a22 += h4.z * w4.z; a23 += h4.z * w4.w;
                a30 += h4.w * w4.x; a31 += h4.w * w4.y; a32 += h4.w * w4.z; a33 += h4.w * w4.w;
            }
            float* zpr = &zp[kseg * 260 + tile * 16];
            *(float4*)(zpr + 0)  = make_float4(a00, a01, a02, a03);
            *(float4*)(zpr + 4)  = make_float4(a10, a11, a12, a13);
            *(float4*)(zpr + 8)  = make_float4(a20, a21, a22, a23);
            *(float4*)(zpr + 12) = make_float4(a30, a31, a32, a33);
        }
        __syncthreads();

        // reduce 16 kseg partials -> zfull[b][jj]
        {
            float s = 0.f;
            #pragma unroll
            for (int ks = 0; ks < 16; ++ks) s += zp[ks * 260 + tile2 * 16 + e];
            zfull[rb][rjj] = s;
        }
        __syncthreads();

        // gate math (wave 0): thread (gb, kp)
        if (tid < 64) {
            float zi = zfull[gb][0 * 2 + (tid >> 5)] + zp4[0];
            float zF = zfull[gb][1 * 2 + (tid >> 5)] + zp4[1];
            float zg = zfull[gb][2 * 2 + (tid >> 5)] + zp4[2];
            float zo = zfull[gb][3 * 2 + (tid >> 5)] + zp4[3];
            float si = 1.f / (1.f + expf(-zi));
            float sf = 1.f / (1.f + expf(-zF));
            float so = 1.f / (1.f + expf(-zo));
            float c_new = sf * c_reg + si * tanhf(zg);
            float h_new = so * tanhf(c_new);
            c_reg = c_new;
            hout[gkk * BATCH + gb] = h_new;
            h_seq[((size_t)(gb * TSEQ + t)) * HDIM + gkk] = (t < glen) ? h_new : 0.f;
        }
        gridbar(bar, t, bid);
    }
}

// ---------------------------------------------------------------- fill masked logits rows with bias
__launch_bounds__(256)
__global__ void fill_masked(const int* __restrict__ lengths,
                            const float* __restrict__ blog,
                            float* __restrict__ logits) {
    int row = blockIdx.x;
    int b = row >> 6, t = row & 63;
    if (t < lengths[b]) return;
    float* p = logits + (size_t)row * VOCAB;
    for (int v = threadIdx.x * 4; v < VOCAB; v += 256 * 4) {
        float4 o;
        o.x = blog[v + 0]; o.y = blog[v + 1]; o.z = blog[v + 2]; o.w = blog[v + 3];
        *(float4*)(p + v) = o;
    }
}

// ---------------------------------------------------------------- logits GEMM over compacted rows
// 128x128 tile, 256 thr, 8x8 per thread (split 4+64), XCD-chunked swizzled 1-D grid.
__launch_bounds__(256)
__global__ void gemm_logits128(const float* __restrict__ A,      // h_seq
                               const int* __restrict__ rowlist,
                               const int* __restrict__ mactp,
                               const float* __restrict__ Bm,     // W_logits
                               const float* __restrict__ blog,
                               float* __restrict__ C) {
    const int Mact = *mactp;
    // bijective XCD-chunk swizzle (nwg = 4000, 4000 % 8 == 0)
    const int chunk = gridDim.x >> 3;                 // 500
    const int L = (blockIdx.x & 7) * chunk + (blockIdx.x >> 3);
    const int m0 = (L & 15) * 128;                    // m-tile fast
    const int n0 = (L >> 4) * 128;                    // n-tile slow
    if (m0 >= Mact) return;

    __shared__ __align__(16) float As[16][132];       // [k][m]
    __shared__ __align__(16) float Bs[16][132];       // [k][n]
    const int tid = threadIdx.x;
    const int tx = tid & 15, ty = tid >> 4;

    const int am  = tid >> 2;                         // 0..63
    const int akq = (tid & 3) << 2;                   // 0,4,8,12
    const size_t arow0 = (size_t)rowlist[m0 + am]      * HDIM;
    const size_t arow1 = (size_t)rowlist[m0 + 64 + am] * HDIM;
    const int bk = tid >> 5;                          // 0..7
    const int bc = (tid & 31) << 2;                   // 0..124

    float c00[4][4] = {}, c01[4][4] = {}, c10[4][4] = {}, c11[4][4] = {};

    for (int k0 = 0; k0 < HDIM; k0 += 16) {
        const float4 av0 = *(const float4*)(A + arow0 + k0 + akq);
        const float4 av1 = *(const float4*)(A + arow1 + k0 + akq);
        As[akq + 0][am] = av0.x;
        As[akq + 1][am] = av0.y;
        As[akq + 2][am] = av0.z;
        As[akq + 3][am] = av0.w;
        As[akq + 0][64 + am] = av1.x;
        As[akq + 1][64 + am] = av1.y;
        As[akq + 2][64 + am] = av1.z;
        As[akq + 3][64 + am] = av1.w;
        const float4 bv0 = *(const float4*)(Bm + (size_t)(k0 + bk)     * VOCAB + n0 + bc);
        const float4 bv1 = *(const float4*)(Bm + (size_t)(k0 + 8 + bk) * VOCAB + n0 + bc);
        *(float4*)&Bs[bk][bc]     = bv0;
        *(float4*)&Bs[bk + 8][bc] = bv1;
        __syncthreads();
        #pragma unroll
        for (int kk = 0; kk < 16; ++kk) {
            const float4 aL = *(const float4*)&As[kk][ty << 2];
            const float4 aH = *(const float4*)&As[kk][64 + (ty << 2)];
            const float4 bL = *(const float4*)&Bs[kk][tx << 2];
            const float4 bH = *(const float4*)&Bs[kk][64 + (tx << 2)];
            const float a_[8] = {aL.x, aL.y, aL.z, aL.w, aH.x, aH.y, aH.z, aH.w};
            const float b_[8] = {bL.x, bL.y, bL.z, bL.w, bH.x, bH.y, bH.z, bH.w};
            #pragma unroll
            for (int i = 0; i < 4; ++i) {
                #pragma unroll
                for (int j = 0; j < 4; ++j) {
                    c00[i][j] += a_[i]     * b_[j];
                    c01[i][j] += a_[i]     * b_[4 + j];
                    c10[i][j] += a_[4 + i] * b_[j];
                    c11[i][j] += a_[4 + i] * b_[4 + j];
                }
            }
        }
        __syncthreads();
    }

    const int nL = n0 + (tx << 2);
    const int nH = nL + 64;
    const float4 gL = *(const float4*)(blog + nL);
    const float4 gH = *(const float4*)(blog + nH);
    const float gLa[4] = {gL.x, gL.y, gL.z, gL.w};
    const float gHa[4] = {gH.x, gH.y, gH.z, gH.w};
    #pragma unroll
    for (int i = 0; i < 4; ++i) {
        const int mL = m0 + (ty << 2) + i;
        if (mL < Mact) {
            const size_t rm = (size_t)rowlist[mL] * VOCAB;
            float4 oL, oH;
            oL.x = c00[i][0] + gLa[0]; oL.y = c00[i][1] + gLa[1];
            oL.z = c00[i][2] + gLa[2]; oL.w = c00[i][3] + gLa[3];
            oH.x = c01[i][0] + gHa[0]; oH.y = c01[i][1] + gHa[1];
            oH.z = c01[i][2] + gHa[2]; oH.w = c01[i][3] + gHa[3];
            *(float4*)(C + rm + nL) = oL;
            *(float4*)(C + rm + nH) = oH;
        }
        const int mH = mL + 64;
        if (mH < Mact) {
            const size_t rm = (size_t)rowlist[mH] * VOCAB;
            float4 oL, oH;
            oL.x = c10[i][0] + gLa[0]; oL.y = c10[i][1] + gLa[1];
            oL.z = c10[i][2] + gLa[2]; oL.w = c10[i][3] + gLa[3];
            oH.x = c11[i][0] + gHa[0]; oH.y = c11[i][1] + gHa[1];
            oH.z = c11[i][2] + gHa[2]; oH.w = c11[i][3] + gHa[3];
            *(float4*)(C + rm + nL) = oL;
            *(float4*)(C + rm + nH) = oH;
        }
    }
}

// ---------------------------------------------------------------- argmax per row (first occurrence)
__launch_bounds__(256)
__global__ void argmax_kernel(const float* __restrict__ logits, float* __restrict__ outa) {
    const int row = blockIdx.x;
    const int tid = threadIdx.x;
    const float* p = logits + (size_t)row * VOCAB;
    float bv = -INFINITY; int bi = VOCAB;
    for (int v = tid; v < VOCAB; v += 256) {
        float x = p[v];
        if (x > bv) { bv = x; bi = v; }
    }
    __shared__ float sv[256];
    __shared__ int   si[256];
    sv[tid] = bv; si[tid] = bi;
    __syncthreads();
    for (int s = 128; s > 0; s >>= 1) {
        if (tid < s) {
            if (sv[tid + s] > sv[tid] || (sv[tid + s] == sv[tid] && si[tid + s] < si[tid])) {
                sv[tid] = sv[tid + s]; si[tid] = si[tid + s];
            }
        }
        __syncthreads();
    }
    if (tid == 0) outa[row] = (float)si[0];
}

// ---------------------------------------------------------------- launcher
extern "C" void kernel_launch(void* const* d_in, const int* in_sizes, int n_in,
                              void* d_out, int out_size, void* d_ws, size_t ws_size,
                              hipStream_t stream) {
    const int*   topk     = (const int*)d_in[0];
    const float* img      = (const float*)d_in[1];
    const int*   seq      = (const int*)d_in[2];
    const int*   lengths  = (const int*)d_in[3];
    const float* word_emb = (const float*)d_in[4];
    const float* attr_emb = (const float*)d_in[5];
    const float* Wk       = (const float*)d_in[6];
    const float* bias     = (const float*)d_in[7];
    const float* Wlog     = (const float*)d_in[8];
    const float* blog     = (const float*)d_in[9];

    float* out_logits = (float*)d_out;
    float* out_argmax = out_logits + (size_t)BATCH * TSEQ * VOCAB;

    // ws layout (floats): mean_attr | zf | cbuf(barrier) | hb0 | hb1 | h_seq | Whr | rowlist | mact
    float* ws        = (float*)d_ws;
    float* mean_attr = ws;
    float* zf        = mean_attr + BATCH * DA;              // 9600
    float* cbuf      = zf + BATCH * G4;                     // 65536 floats: barrier counters live here
    float* hb0       = cbuf + HDIM * BATCH;                 // 16384
    float* hb1       = hb0 + HDIM * BATCH;
    float* h_seq     = hb1 + HDIM * BATCH;
    float* Whr       = h_seq + (size_t)BATCH * TSEQ * HDIM; // 4 MB
    int*   rowlist   = (int*)(Whr + (size_t)256 * 4096);
    int*   mact      = rowlist + BATCH * TSEQ;
    int*   bar       = (int*)cbuf;                          // gcnt[32]*32 | rcnt@2048 | epoch@2080
    // z_pre [2048 rows][2048 j] staged in d_out's logits region; fully consumed
    // by the scan before fill/logits overwrite it.
    float* z_pre     = out_logits;

    // zero h0 ping-pong buffers + barrier counters
    zero_kernel<<<dim3((2 * HDIM * BATCH + 255) / 256), 256, 0, stream>>>(hb0, 2 * HDIM * BATCH);
    zero_kernel<<<dim3(16), 256, 0, stream>>>(cbuf, 4096);

    build_rows<<<1, 256, 0, stream>>>(lengths, rowlist, mact);

    whr_kernel<<<dim3(256), 256, 0, stream>>>(Wk, Whr);

    mean_attr_kernel<<<dim3(BATCH), 320, 0, stream>>>(topk, attr_emb, mean_attr);

    zf_kernel<<<dim3(G4 / 256, BATCH), 256, 0, stream>>>(img, mean_attr, Wk, bias, zf);

    // z_pre[b*T+t][j] = word_emb[seq]@Wx + zf[b][j]
    gemm_tile<true, true><<<dim3(G4 / 64, (BATCH * TSEQ) / 64), 256, 0, stream>>>(
        word_emb, seq, Wk, zf, z_pre, BATCH * TSEQ, G4, DE, DE);

    // persistent scan: 1 cooperative launch (co-residency), custom barrier between steps
    {
        void* kargs[] = {(void*)&z_pre, (void*)&Whr, (void*)&hb0, (void*)&hb1,
                         (void*)&h_seq, (void*)&lengths, (void*)&bar};
        hipLaunchCooperativeKernel((const void*)lstm_scan, dim3(256), dim3(256),
                                   kargs, 0, stream);
    }

    fill_masked<<<dim3(BATCH * TSEQ), 256, 0, stream>>>(lengths, blog, out_logits);

    // 128x128 tile, m-fast + XCD-chunked swizzle: 4000 blocks
    gemm_logits128<<<dim3((VOCAB / 128) * ((BATCH * TSEQ) / 128)), 256, 0, stream>>>(
        h_seq, rowlist, mact, Wlog, blog, out_logits);

    argmax_kernel<<<dim3(BATCH * TSEQ), 256, 0, stream>>>(out_logits, out_argmax);
}

// Round 6
// 1381.667 us; speedup vs baseline: 2.3024x; 1.7702x over previous
//
#include <hip/hip_runtime.h>
#include <hip/hip_bf16.h>
#include <math.h>

#define BATCH 32
#define TSEQ  64
#define KATTR 5
#define VOCAB 32000
#define DE    300
#define DA    300
#define DI    2048
#define HDIM  512
#define G4    2048            // 4*H
#define WOFF  (DE + DI + DA)  // recurrent rows offset in lstm_kernel

// ---------------------------------------------------------------- utility
__global__ void zero_kernel(float* __restrict__ p, int n) {
    int i = blockIdx.x * blockDim.x + threadIdx.x;
    if (i < n) p[i] = 0.f;
}

// order-preserving float->uint key: a > b  <=>  fkey(a) > fkey(b)
__device__ __forceinline__ unsigned int fkey(float f) {
    unsigned int u = __float_as_uint(f);
    return (u & 0x80000000u) ? ~u : (u | 0x80000000u);
}
__device__ __forceinline__ void amax_upd(unsigned int& bk, int& bi, float v, int idx) {
    unsigned int k = fkey(v);
    if (k > bk || (k == bk && idx < bi)) { bk = k; bi = idx; }
}

// ---------------------------------------------------------------- K1: mean attr embedding
__global__ void mean_attr_kernel(const int* __restrict__ topk,
                                 const float* __restrict__ attr_emb,
                                 float* __restrict__ mean_attr) {
    int b = blockIdx.x;
    int tid = threadIdx.x;
    if (tid < DA) {
        float s = 0.f;
        #pragma unroll
        for (int q = 0; q < KATTR; ++q) {
            int a = topk[b * KATTR + q];
            s += attr_emb[(size_t)a * DA + tid];
        }
        mean_attr[b * DA + tid] = s / (float)KATTR;
    }
}

// ---------------------------------------------------------------- K2: zf[b][j] = bias + img@Wimg + mean_attr@Wattr
__launch_bounds__(256)
__global__ void zf_kernel(const float* __restrict__ img,
                          const float* __restrict__ mean_attr,
                          const float* __restrict__ Wk,
                          const float* __restrict__ bias,
                          float* __restrict__ zf) {
    int b = blockIdx.y;
    int j = blockIdx.x * 256 + threadIdx.x;
    float acc = bias[j];
    const float* wimg = Wk + (size_t)DE * G4 + j;
    const float* irow = img + b * DI;
    #pragma unroll 8
    for (int k = 0; k < DI; ++k) acc += irow[k] * wimg[(size_t)k * G4];
    const float* wattr = Wk + (size_t)(DE + DI) * G4 + j;
    const float* arow = mean_attr + b * DA;
    #pragma unroll 4
    for (int k = 0; k < DA; ++k) acc += arow[k] * wattr[(size_t)k * G4];
    zf[b * G4 + j] = acc;
}

// ---------------------------------------------------------------- Wh reshuffle: Whr[bid][k][jj]  jj = g*2+p, col = g*512 + bid*2 + p
__launch_bounds__(256)
__global__ void whr_kernel(const float* __restrict__ Wk, float* __restrict__ Whr) {
    const int bid = blockIdx.x;
    const int tid = threadIdx.x;
    for (int it = 0; it < 16; ++it) {
        int Q = it * 256 + tid;           // 0..4095
        int k = Q >> 3, jj = Q & 7;
        int g = jj >> 1, p = jj & 1;
        Whr[(size_t)bid * 4096 + Q] = Wk[(size_t)(WOFF + k) * G4 + g * HDIM + bid * 2 + p];
    }
}

// ---------------------------------------------------------------- tiled fp32 GEMM, 64x64x16, 256 thr, 4x4/thread
// PERROW: add = addv[(m>>6)*N + n]; else add = addv[n]
template<bool GATHER, bool PERROW>
__launch_bounds__(256)
__global__ void gemm_tile(const float* __restrict__ A,
                          const int* __restrict__ gidx,
                          const float* __restrict__ Bm,
                          const float* __restrict__ addv,
                          float* __restrict__ C,
                          int M, int N, int K, int lda) {
    __shared__ __align__(16) float As[16][68];
    __shared__ __align__(16) float Bs[16][68];
    const int tid = threadIdx.x;
    const int n0 = blockIdx.x * 64;
    const int m0 = blockIdx.y * 64;
    const int tx = tid & 15, ty = tid >> 4;
    const int ar  = tid >> 2;
    const int akq = (tid & 3) << 2;
    const int bkr = tid >> 4;
    const int bc  = (tid & 15) << 2;

    size_t arow;
    if (GATHER) arow = (size_t)gidx[m0 + ar] * (size_t)lda;
    else        arow = (size_t)(m0 + ar) * (size_t)lda;

    float a00=0,a01=0,a02=0,a03=0, a10=0,a11=0,a12=0,a13=0;
    float a20=0,a21=0,a22=0,a23=0, a30=0,a31=0,a32=0,a33=0;

    for (int k0 = 0; k0 < K; k0 += 16) {
        int ka = k0 + akq;
        float4 av;
        if (ka + 4 <= K) {
            av = *(const float4*)(A + arow + ka);
        } else {
            av.x = (ka + 0 < K) ? A[arow + ka + 0] : 0.f;
            av.y = (ka + 1 < K) ? A[arow + ka + 1] : 0.f;
            av.z = (ka + 2 < K) ? A[arow + ka + 2] : 0.f;
            av.w = (ka + 3 < K) ? A[arow + ka + 3] : 0.f;
        }
        As[akq + 0][ar] = av.x;
        As[akq + 1][ar] = av.y;
        As[akq + 2][ar] = av.z;
        As[akq + 3][ar] = av.w;

        int kb = k0 + bkr;
        float4 bv;
        if (kb < K) bv = *(const float4*)(Bm + (size_t)kb * N + n0 + bc);
        else { bv.x = bv.y = bv.z = bv.w = 0.f; }
        *(float4*)&Bs[bkr][bc] = bv;

        __syncthreads();
        #pragma unroll
        for (int kk = 0; kk < 16; ++kk) {
            const float4 a4 = *(const float4*)&As[kk][ty << 2];
            const float4 b4 = *(const float4*)&Bs[kk][tx << 2];
            a00 += a4.x * b4.x; a01 += a4.x * b4.y; a02 += a4.x * b4.z; a03 += a4.x * b4.w;
            a10 += a4.y * b4.x; a11 += a4.y * b4.y; a12 += a4.y * b4.z; a13 += a4.y * b4.w;
            a20 += a4.z * b4.x; a21 += a4.z * b4.y; a22 += a4.z * b4.z; a23 += a4.z * b4.w;
            a30 += a4.w * b4.x; a31 += a4.w * b4.y; a32 += a4.w * b4.z; a33 += a4.w * b4.w;
        }
        __syncthreads();
    }

    float accs[4][4] = {{a00,a01,a02,a03},{a10,a11,a12,a13},{a20,a21,a22,a23},{a30,a31,a32,a33}};
    const int n = n0 + (tx << 2);
    #pragma unroll
    for (int i = 0; i < 4; ++i) {
        int m = m0 + (ty << 2) + i;
        const float* av2 = PERROW ? (addv + (size_t)(m >> 6) * N) : addv;
        float4 o;
        o.x = accs[i][0] + av2[n + 0];
        o.y = accs[i][1] + av2[n + 1];
        o.z = accs[i][2] + av2[n + 2];
        o.w = accs[i][3] + av2[n + 3];
        *(float4*)(C + (size_t)m * N + n) = o;
    }
}

// ---------------------------------------------------------------- row compaction list
__global__ void build_rows(const int* __restrict__ lengths,
                           int* __restrict__ rowlist, int* __restrict__ mact) {
    __shared__ int len[BATCH];
    __shared__ int off[BATCH + 1];
    int tid = threadIdx.x;
    if (tid < BATCH) len[tid] = lengths[tid];
    __syncthreads();
    if (tid == 0) {
        int s = 0;
        for (int b = 0; b < BATCH; ++b) { off[b] = s; s += len[b]; }
        off[BATCH] = s;
        *mact = s;
    }
    __syncthreads();
    int total = off[BATCH];
    for (int i = tid; i < BATCH * TSEQ; i += 256) {
        int b = i >> 6, t = i & 63;
        if (t < len[b]) rowlist[off[b] + t] = i;
    }
    for (int i = tid; i < BATCH * TSEQ; i += 256) {
        if (i >= total) rowlist[i] = 0;
    }
}

// ---------------------------------------------------------------- one LSTM step, 256 blocks x 256 thr (R1-proven)
// block bid owns kouts {bid*2, bid*2+1}; j-cols jj=g*2+p -> g*512 + bid*2 + p.
// h in global [k][b]; per-thread register tile 4b x 4j over a 32-k segment.
__launch_bounds__(256, 1)
__global__ void lstm_step2(const float* __restrict__ z_pre,   // [B*T][2048]
                           const float* __restrict__ Whr,     // [256][512][8]
                           const float* __restrict__ hin,     // [512][32]
                           float* __restrict__ hout,          // [512][32]
                           float* __restrict__ cbuf,          // [512][32]
                           float* __restrict__ h_seq,         // [B*T][512]
                           const int* __restrict__ lengths,
                           int t) {
    __shared__ __align__(16) float hsT[HDIM][36];   // [k][b], stride 36 (144B)
    __shared__ __align__(16) float wsm[HDIM][12];   // [k][jj], stride 12 (48B)
    __shared__ __align__(16) float zp[16 * 260];    // [kseg][tile*16+e], row pad +4
    __shared__ float zfull[BATCH][8];
    const int bid = blockIdx.x;
    const int tid = threadIdx.x;

    // early scalar prefetches for the gate phase (independent of staging)
    float zp4[4] = {0, 0, 0, 0};
    int glen = 0, gb = 0, gkk = 0;
    float c_old = 0.f;
    if (tid < 64) {
        gb = tid & 31;
        int kp = tid >> 5;
        gkk = bid * 2 + kp;
        glen = lengths[gb];
        const float* zr = z_pre + ((size_t)(gb * TSEQ + t)) * G4 + gkk;
        zp4[0] = zr[0 * HDIM];
        zp4[1] = zr[1 * HDIM];
        zp4[2] = zr[2 * HDIM];
        zp4[3] = zr[3 * HDIM];
        c_old = cbuf[gkk * BATCH + gb];
    }

    // stage h: 16384 floats, coalesced float4
    #pragma unroll
    for (int it = 0; it < 16; ++it) {
        int Q = it * 256 + tid;          // quad index; addr = 4Q floats
        int k = Q >> 3, bq = Q & 7;
        float4 v = *(const float4*)(hin + (size_t)Q * 4);
        *(float4*)&hsT[k][bq * 4] = v;
    }
    // stage W slice: 4096 floats contiguous
    const float* wsrc = Whr + (size_t)bid * 4096;
    #pragma unroll
    for (int it = 0; it < 4; ++it) {
        int Q = it * 256 + tid;          // 0..1023
        int k = Q >> 1, jjq = Q & 1;
        float4 v = *(const float4*)(wsrc + (size_t)Q * 4);
        *(float4*)&wsm[k][jjq * 4] = v;
    }
    __syncthreads();

    // compute: thread = (kseg, tile); tile -> 4b x 4j
    {
        const int kseg = tid >> 4;
        const int tile = tid & 15;
        const int b0 = (tile >> 1) << 2;
        const int j0 = (tile & 1) << 2;
        const int kb = kseg << 5;
        float a00=0,a01=0,a02=0,a03=0, a10=0,a11=0,a12=0,a13=0;
        float a20=0,a21=0,a22=0,a23=0, a30=0,a31=0,a32=0,a33=0;
        #pragma unroll 8
        for (int kk = 0; kk < 32; ++kk) {
            const int k = kb + kk;
            const float4 h4 = *(const float4*)&hsT[k][b0];
            const float4 w4 = *(const float4*)&wsm[k][j0];
            a00 += h4.x * w4.x; a01 += h4.x * w4.y; a02 += h4.x * w4.z; a03 += h4.x * w4.w;
            a10 += h4.y * w4.x; a11 += h4.y * w4.y; a12 += h4.y * w4.z; a13 += h4.y * w4.w;
            a20 += h4.z * w4.x; a21 += h4.z * w4.y; a22 += h4.z * w4.z; a23 += h4.z * w4.w;
            a30 += h4.w * w4.x; a31 += h4.w * w4.y; a32 += h4.w * w4.z; a33 += h4.w * w4.w;
        }
        float* zpr = &zp[kseg * 260 + tile * 16];
        *(float4*)(zpr + 0)  = make_float4(a00, a01, a02, a03);
        *(float4*)(zpr + 4)  = make_float4(a10, a11, a12, a13);
        *(float4*)(zpr + 8)  = make_float4(a20, a21, a22, a23);
        *(float4*)(zpr + 12) = make_float4(a30, a31, a32, a33);
    }
    __syncthreads();

    // reduce 16 kseg partials -> zfull[b][jj]
    {
        const int b = tid & 31, jj = tid >> 5;
        const int tile2 = ((b >> 2) << 1) + (jj >> 2);
        const int e = ((b & 3) << 2) + (jj & 3);
        float s = 0.f;
        #pragma unroll
        for (int ks = 0; ks < 16; ++ks) s += zp[ks * 260 + tile2 * 16 + e];
        zfull[b][jj] = s;
    }
    __syncthreads();

    // gate math (wave 0): thread (gb, kp)
    if (tid < 64) {
        const int kp = tid >> 5;
        float zi = zfull[gb][0 * 2 + kp] + zp4[0];
        float zF = zfull[gb][1 * 2 + kp] + zp4[1];
        float zg = zfull[gb][2 * 2 + kp] + zp4[2];
        float zo = zfull[gb][3 * 2 + kp] + zp4[3];
        float si = 1.f / (1.f + expf(-zi));
        float sf = 1.f / (1.f + expf(-zF));
        float so = 1.f / (1.f + expf(-zo));
        float c_new = sf * c_old + si * tanhf(zg);
        float h_new = so * tanhf(c_new);
        cbuf[gkk * BATCH + gb] = c_new;
        hout[gkk * BATCH + gb] = h_new;
        h_seq[((size_t)(gb * TSEQ + t)) * HDIM + gkk] = (t < glen) ? h_new : 0.f;
    }
}

// ---------------------------------------------------------------- fill masked logits rows with bias
__launch_bounds__(256)
__global__ void fill_masked(const int* __restrict__ lengths,
                            const float* __restrict__ blog,
                            float* __restrict__ logits) {
    int row = blockIdx.x;
    int b = row >> 6, t = row & 63;
    if (t < lengths[b]) return;
    float* p = logits + (size_t)row * VOCAB;
    for (int v = threadIdx.x * 4; v < VOCAB; v += 256 * 4) {
        float4 o;
        o.x = blog[v + 0]; o.y = blog[v + 1]; o.z = blog[v + 2]; o.w = blog[v + 3];
        *(float4*)(p + v) = o;
    }
}

// ---------------------------------------------------------------- logits GEMM over compacted rows + fused argmax
// 128x128 tile, 256 thr, 8x8 per thread (split 4+64), XCD-chunked swizzled 1-D grid.
// Epilogue: per-row packed (fkey<<32 | ~col) 16-lane shuffle reduce -> atomicMax(u64).
__launch_bounds__(256)
__global__ void gemm_logits128(const float* __restrict__ A,      // h_seq
                               const int* __restrict__ rowlist,
                               const int* __restrict__ mactp,
                               const float* __restrict__ Bm,     // W_logits
                               const float* __restrict__ blog,
                               float* __restrict__ C,
                               unsigned long long* __restrict__ packed) {
    const int Mact = *mactp;
    // bijective XCD-chunk swizzle (nwg = 4000, 4000 % 8 == 0)
    const int chunk = gridDim.x >> 3;                 // 500
    const int L = (blockIdx.x & 7) * chunk + (blockIdx.x >> 3);
    const int m0 = (L & 15) * 128;                    // m-tile fast
    const int n0 = (L >> 4) * 128;                    // n-tile slow
    if (m0 >= Mact) return;

    __shared__ __align__(16) float As[16][132];       // [k][m]
    __shared__ __align__(16) float Bs[16][132];       // [k][n]
    const int tid = threadIdx.x;
    const int tx = tid & 15, ty = tid >> 4;

    const int am  = tid >> 2;                         // 0..63
    const int akq = (tid & 3) << 2;                   // 0,4,8,12
    const size_t arow0 = (size_t)rowlist[m0 + am]      * HDIM;
    const size_t arow1 = (size_t)rowlist[m0 + 64 + am] * HDIM;
    const int bk = tid >> 5;                          // 0..7
    const int bc = (tid & 31) << 2;                   // 0..124

    float c00[4][4] = {}, c01[4][4] = {}, c10[4][4] = {}, c11[4][4] = {};

    for (int k0 = 0; k0 < HDIM; k0 += 16) {
        const float4 av0 = *(const float4*)(A + arow0 + k0 + akq);
        const float4 av1 = *(const float4*)(A + arow1 + k0 + akq);
        As[akq + 0][am] = av0.x;
        As[akq + 1][am] = av0.y;
        As[akq + 2][am] = av0.z;
        As[akq + 3][am] = av0.w;
        As[akq + 0][64 + am] = av1.x;
        As[akq + 1][64 + am] = av1.y;
        As[akq + 2][64 + am] = av1.z;
        As[akq + 3][64 + am] = av1.w;
        const float4 bv0 = *(const float4*)(Bm + (size_t)(k0 + bk)     * VOCAB + n0 + bc);
        const float4 bv1 = *(const float4*)(Bm + (size_t)(k0 + 8 + bk) * VOCAB + n0 + bc);
        *(float4*)&Bs[bk][bc]     = bv0;
        *(float4*)&Bs[bk + 8][bc] = bv1;
        __syncthreads();
        #pragma unroll
        for (int kk = 0; kk < 16; ++kk) {
            const float4 aL = *(const float4*)&As[kk][ty << 2];
            const float4 aH = *(const float4*)&As[kk][64 + (ty << 2)];
            const float4 bL = *(const float4*)&Bs[kk][tx << 2];
            const float4 bH = *(const float4*)&Bs[kk][64 + (tx << 2)];
            const float a_[8] = {aL.x, aL.y, aL.z, aL.w, aH.x, aH.y, aH.z, aH.w};
            const float b_[8] = {bL.x, bL.y, bL.z, bL.w, bH.x, bH.y, bH.z, bH.w};
            #pragma unroll
            for (int i = 0; i < 4; ++i) {
                #pragma unroll
                for (int j = 0; j < 4; ++j) {
                    c00[i][j] += a_[i]     * b_[j];
                    c01[i][j] += a_[i]     * b_[4 + j];
                    c10[i][j] += a_[4 + i] * b_[j];
                    c11[i][j] += a_[4 + i] * b_[4 + j];
                }
            }
        }
        __syncthreads();
    }

    const int nL = n0 + (tx << 2);
    const int nH = nL + 64;
    const float4 gL = *(const float4*)(blog + nL);
    const float4 gH = *(const float4*)(blog + nH);
    const float gLa[4] = {gL.x, gL.y, gL.z, gL.w};
    const float gHa[4] = {gH.x, gH.y, gH.z, gH.w};
    #pragma unroll
    for (int i = 0; i < 4; ++i) {
        const int mL = m0 + (ty << 2) + i;
        if (mL < Mact) {
            const int rid = rowlist[mL];
            const size_t rm = (size_t)rid * VOCAB;
            float4 oL, oH;
            oL.x = c00[i][0] + gLa[0]; oL.y = c00[i][1] + gLa[1];
            oL.z = c00[i][2] + gLa[2]; oL.w = c00[i][3] + gLa[3];
            oH.x = c01[i][0] + gHa[0]; oH.y = c01[i][1] + gHa[1];
            oH.z = c01[i][2] + gHa[2]; oH.w = c01[i][3] + gHa[3];
            *(float4*)(C + rm + nL) = oL;
            *(float4*)(C + rm + nH) = oH;
            // fused argmax: local best over 8 cols, 16-lane reduce, one atomic
            unsigned int bkk = 0u; int bii = 0x7FFFFFFF;
            amax_upd(bkk, bii, oL.x, nL + 0); amax_upd(bkk, bii, oL.y, nL + 1);
            amax_upd(bkk, bii, oL.z, nL + 2); amax_upd(bkk, bii, oL.w, nL + 3);
            amax_upd(bkk, bii, oH.x, nH + 0); amax_upd(bkk, bii, oH.y, nH + 1);
            amax_upd(bkk, bii, oH.z, nH + 2); amax_upd(bkk, bii, oH.w, nH + 3);
            unsigned long long pv = ((unsigned long long)bkk << 32) | (unsigned int)(~bii);
            #pragma unroll
            for (int off = 8; off > 0; off >>= 1) {
                unsigned int hi = (unsigned int)(pv >> 32), lo = (unsigned int)pv;
                unsigned int ohi = __shfl_xor(hi, off, 16);
                unsigned int olo = __shfl_xor(lo, off, 16);
                unsigned long long ov = ((unsigned long long)ohi << 32) | olo;
                if (ov > pv) pv = ov;
            }
            if (tx == 0) atomicMax(&packed[rid], pv);
        }
        const int mH = mL + 64;
        if (mH < Mact) {
            const int rid = rowlist[mH];
            const size_t rm = (size_t)rid * VOCAB;
            float4 oL, oH;
            oL.x = c10[i][0] + gLa[0]; oL.y = c10[i][1] + gLa[1];
            oL.z = c10[i][2] + gLa[2]; oL.w = c10[i][3] + gLa[3];
            oH.x = c11[i][0] + gHa[0]; oH.y = c11[i][1] + gHa[1];
            oH.z = c11[i][2] + gHa[2]; oH.w = c11[i][3] + gHa[3];
            *(float4*)(C + rm + nL) = oL;
            *(float4*)(C + rm + nH) = oH;
            unsigned int bkk = 0u; int bii = 0x7FFFFFFF;
            amax_upd(bkk, bii, oL.x, nL + 0); amax_upd(bkk, bii, oL.y, nL + 1);
            amax_upd(bkk, bii, oL.z, nL + 2); amax_upd(bkk, bii, oL.w, nL + 3);
            amax_upd(bkk, bii, oH.x, nH + 0); amax_upd(bkk, bii, oH.y, nH + 1);
            amax_upd(bkk, bii, oH.z, nH + 2); amax_upd(bkk, bii, oH.w, nH + 3);
            unsigned long long pv = ((unsigned long long)bkk << 32) | (unsigned int)(~bii);
            #pragma unroll
            for (int off = 8; off > 0; off >>= 1) {
                unsigned int hi = (unsigned int)(pv >> 32), lo = (unsigned int)pv;
                unsigned int ohi = __shfl_xor(hi, off, 16);
                unsigned int olo = __shfl_xor(lo, off, 16);
                unsigned long long ov = ((unsigned long long)ohi << 32) | olo;
                if (ov > pv) pv = ov;
            }
            if (tx == 0) atomicMax(&packed[rid], pv);
        }
    }
}

// ---------------------------------------------------------------- finalize: bias argmax for masked rows + unpack
__launch_bounds__(256)
__global__ void finalize_argmax(const unsigned long long* __restrict__ packed,
                                const float* __restrict__ blog,
                                const int* __restrict__ lengths,
                                float* __restrict__ outa) {
    __shared__ unsigned long long red[256];
    __shared__ int slen[BATCH];
    const int tid = threadIdx.x;
    // bias argmax (first occurrence)
    unsigned int bk = 0u; int bi = 0x7FFFFFFF;
    for (int v = tid; v < VOCAB; v += 256) {
        amax_upd(bk, bi, blog[v], v);
    }
    red[tid] = ((unsigned long long)bk << 32) | (unsigned int)(~bi);
    if (tid < BATCH) slen[tid] = lengths[tid];
    __syncthreads();
    for (int s = 128; s > 0; s >>= 1) {
        if (tid < s) { if (red[tid + s] > red[tid]) red[tid] = red[tid + s]; }
        __syncthreads();
    }
    const int bias_idx = (int)(~(unsigned int)(red[0] & 0xFFFFFFFFull));
    for (int row = tid; row < BATCH * TSEQ; row += 256) {
        int b = row >> 6, t = row & 63;
        int idx = (t < slen[b]) ? (int)(~(unsigned int)(packed[row] & 0xFFFFFFFFull))
                                : bias_idx;
        outa[row] = (float)idx;
    }
}

// ---------------------------------------------------------------- launcher
extern "C" void kernel_launch(void* const* d_in, const int* in_sizes, int n_in,
                              void* d_out, int out_size, void* d_ws, size_t ws_size,
                              hipStream_t stream) {
    const int*   topk     = (const int*)d_in[0];
    const float* img      = (const float*)d_in[1];
    const int*   seq      = (const int*)d_in[2];
    const int*   lengths  = (const int*)d_in[3];
    const float* word_emb = (const float*)d_in[4];
    const float* attr_emb = (const float*)d_in[5];
    const float* Wk       = (const float*)d_in[6];
    const float* bias     = (const float*)d_in[7];
    const float* Wlog     = (const float*)d_in[8];
    const float* blog     = (const float*)d_in[9];

    float* out_logits = (float*)d_out;
    float* out_argmax = out_logits + (size_t)BATCH * TSEQ * VOCAB;

    // ws layout (floats): mean_attr | zf | cbuf | hb0 | hb1 | h_seq | Whr | rowlist | mact | packed
    float* ws        = (float*)d_ws;
    float* mean_attr = ws;
    float* zf        = mean_attr + BATCH * DA;              // 9600
    float* cbuf      = zf + BATCH * G4;                     // 65536
    float* hb0       = cbuf + HDIM * BATCH;                 // 16384
    float* hb1       = hb0 + HDIM * BATCH;
    float* h_seq     = hb1 + HDIM * BATCH;
    float* Whr       = h_seq + (size_t)BATCH * TSEQ * HDIM; // 4 MB
    int*   rowlist   = (int*)(Whr + (size_t)256 * 4096);
    int*   mact      = rowlist + BATCH * TSEQ;
    unsigned long long* packed = (unsigned long long*)(mact + 2);  // 8B-aligned (even int offset)
    // z_pre [2048 rows][2048 j] staged in d_out's logits region; fully consumed
    // by the scan before fill/logits overwrite it.
    float* z_pre     = out_logits;

    // zero c and h0 (adjacent) + packed argmax slots (2048 u64 = 4096 floats)
    zero_kernel<<<dim3((2 * HDIM * BATCH + 255) / 256), 256, 0, stream>>>(cbuf, 2 * HDIM * BATCH);
    zero_kernel<<<dim3(16), 256, 0, stream>>>((float*)packed, 4096);

    build_rows<<<1, 256, 0, stream>>>(lengths, rowlist, mact);

    whr_kernel<<<dim3(256), 256, 0, stream>>>(Wk, Whr);

    mean_attr_kernel<<<dim3(BATCH), 320, 0, stream>>>(topk, attr_emb, mean_attr);

    zf_kernel<<<dim3(G4 / 256, BATCH), 256, 0, stream>>>(img, mean_attr, Wk, bias, zf);

    // z_pre[b*T+t][j] = word_emb[seq]@Wx + zf[b][j]
    gemm_tile<true, true><<<dim3(G4 / 64, (BATCH * TSEQ) / 64), 256, 0, stream>>>(
        word_emb, seq, Wk, zf, z_pre, BATCH * TSEQ, G4, DE, DE);

    // sequential scan, one kernel per step (proven 13.7 us/step)
    float* hin = hb0;
    float* hout = hb1;
    for (int t = 0; t < TSEQ; ++t) {
        lstm_step2<<<dim3(256), 256, 0, stream>>>(z_pre, Whr, hin, hout, cbuf, h_seq, lengths, t);
        float* tmp = hin; hin = hout; hout = tmp;
    }

    fill_masked<<<dim3(BATCH * TSEQ), 256, 0, stream>>>(lengths, blog, out_logits);

    // 128x128 tile, m-fast + XCD-chunked swizzle: 4000 blocks; fused argmax
    gemm_logits128<<<dim3((VOCAB / 128) * ((BATCH * TSEQ) / 128)), 256, 0, stream>>>(
        h_seq, rowlist, mact, Wlog, blog, out_logits, packed);

    finalize_argmax<<<dim3(1), 256, 0, stream>>>(packed, blog, lengths, out_argmax);
}